// Round 1
// baseline (31.379 us; speedup 1.0000x reference)
//
#include <hip/hip_runtime.h>
#include <math.h>

#define DIM 1024
#define KK 7
#define DIL 2
#define BATCH 16384
#define NEG 0.01f

// ---------------------------------------------------------------------------
// Precompute per-feature tables (runs once per launch, 1024 threads):
//   ws[0*DIM + i] = scale[i]
//   ws[1*DIM + i] = log(|scale[i]*w0 + 1|)        (act_grad = 1 branch)
//   ws[2*DIM + i] = log(|0.01*scale[i]*w0 + 1|)   (act_grad = 0.01 branch)
// ---------------------------------------------------------------------------
__global__ void cnn_flow_precomp(const float* __restrict__ wgt,
                                 const float* __restrict__ lmbd,
                                 float* __restrict__ ws) {
    int i = blockIdx.x * blockDim.x + threadIdx.x;
    if (i >= DIM) return;
    float w0 = wgt[0];
    float l  = lmbd[i];
    // jax.nn.softplus: max(x,0) + log1p(exp(-|x|))
    float sp = fmaxf(l, 0.0f) + log1pf(expf(-fabsf(l)));
    float scale;
    if (w0 == 0.0f)      scale = l;
    else if (w0 > 0.0f)  scale = -1.0f / w0 + sp;
    else                 scale = -1.0f / w0 - sp;
    ws[i]           = scale;
    ws[DIM + i]     = logf(fabsf(fmaf(scale,        w0, 1.0f)));
    ws[2 * DIM + i] = logf(fabsf(fmaf(NEG * scale,  w0, 1.0f)));
}

// ---------------------------------------------------------------------------
// Main kernel: 1 block = 1 row of x. 256 threads x 4 features each.
// PRE=true  -> read scale/log tables from ws (the normal, fast path)
// PRE=false -> compute transcendentals inline (fallback if ws too small)
// ---------------------------------------------------------------------------
template <bool PRE>
__global__ __launch_bounds__(256)
void cnn_flow_main(const float* __restrict__ x,
                   const float* __restrict__ wgt,
                   const float* __restrict__ bias,
                   const float* __restrict__ lmbd,
                   const float* __restrict__ ws,
                   float* __restrict__ out,
                   float* __restrict__ logdet) {
    const int b    = blockIdx.x;
    const int t    = threadIdx.x;
    const int base = t << 2;                 // 4 features per thread
    const float* xrow = x + (size_t)b * DIM;

    // weights + bias: 8 scalar loads, L2-resident after first wave
    float w[KK];
#pragma unroll
    for (int k = 0; k < KK; ++k) w[k] = wgt[k];
    const float w0 = w[0];
    const float bs = bias[0];

    // 16-float conv window [base, base+16). Features base..base+3 need taps
    // base+2k .. base+3+12. Right zero-pad past DIM.
    float xv[16];
    if (base + 16 <= DIM) {
#pragma unroll
        for (int j = 0; j < 4; ++j) {
            float4 v = *reinterpret_cast<const float4*>(xrow + base + 4 * j);
            xv[4 * j + 0] = v.x; xv[4 * j + 1] = v.y;
            xv[4 * j + 2] = v.z; xv[4 * j + 3] = v.w;
        }
    } else {
#pragma unroll
        for (int j = 0; j < 16; ++j) {
            int idx = base + j;
            xv[j] = (idx < DIM) ? xrow[idx] : 0.0f;
        }
    }

    // per-feature tables
    float sc[4], lp[4], ln[4];
    if (PRE) {
        float4 s = *reinterpret_cast<const float4*>(ws + base);
        float4 p = *reinterpret_cast<const float4*>(ws + DIM + base);
        float4 n = *reinterpret_cast<const float4*>(ws + 2 * DIM + base);
        sc[0] = s.x; sc[1] = s.y; sc[2] = s.z; sc[3] = s.w;
        lp[0] = p.x; lp[1] = p.y; lp[2] = p.z; lp[3] = p.w;
        ln[0] = n.x; ln[1] = n.y; ln[2] = n.z; ln[3] = n.w;
    } else {
        float4 lm = *reinterpret_cast<const float4*>(lmbd + base);
        float lms[4] = {lm.x, lm.y, lm.z, lm.w};
#pragma unroll
        for (int i = 0; i < 4; ++i) {
            float l  = lms[i];
            float sp = fmaxf(l, 0.0f) + log1pf(expf(-fabsf(l)));
            float scale;
            if (w0 == 0.0f)      scale = l;
            else if (w0 > 0.0f)  scale = -1.0f / w0 + sp;
            else                 scale = -1.0f / w0 - sp;
            sc[i] = scale;
            lp[i] = logf(fabsf(fmaf(scale,       w0, 1.0f)));
            ln[i] = logf(fabsf(fmaf(NEG * scale, w0, 1.0f)));
        }
    }

    float ld_acc = 0.0f;
    float o[4];
#pragma unroll
    for (int i = 0; i < 4; ++i) {
        float conv = bs;
#pragma unroll
        for (int k = 0; k < KK; ++k)
            conv = fmaf(xv[i + DIL * k], w[k], conv);
        bool pos  = (conv >= 0.0f);
        float act = pos ? conv : NEG * conv;
        o[i]      = fmaf(act, sc[i], xv[i]);
        ld_acc   += pos ? lp[i] : ln[i];
    }
    *reinterpret_cast<float4*>(out + (size_t)b * DIM + base) =
        make_float4(o[0], o[1], o[2], o[3]);

    // block-reduce logdet: wave64 shuffle tree, then 4-wave LDS combine
#pragma unroll
    for (int off = 32; off > 0; off >>= 1)
        ld_acc += __shfl_down(ld_acc, off, 64);
    __shared__ float red[4];
    const int wave = t >> 6;
    const int lane = t & 63;
    if (lane == 0) red[wave] = ld_acc;
    __syncthreads();
    if (t == 0)
        logdet[b] = (red[0] + red[1]) + (red[2] + red[3]);
}

extern "C" void kernel_launch(void* const* d_in, const int* in_sizes, int n_in,
                              void* d_out, int out_size, void* d_ws, size_t ws_size,
                              hipStream_t stream) {
    const float* x    = (const float*)d_in[0];
    const float* wgt  = (const float*)d_in[1];
    const float* bias = (const float*)d_in[2];
    const float* lmbd = (const float*)d_in[3];
    float* out    = (float*)d_out;                    // (BATCH, DIM)
    float* logdet = out + (size_t)BATCH * DIM;        // (BATCH,)

    const size_t tbl_bytes = 3 * DIM * sizeof(float);
    if (d_ws != nullptr && ws_size >= tbl_bytes) {
        float* ws = (float*)d_ws;
        cnn_flow_precomp<<<(DIM + 255) / 256, 256, 0, stream>>>(wgt, lmbd, ws);
        cnn_flow_main<true><<<BATCH, 256, 0, stream>>>(
            x, wgt, bias, lmbd, ws, out, logdet);
    } else {
        cnn_flow_main<false><<<BATCH, 256, 0, stream>>>(
            x, wgt, bias, lmbd, nullptr, out, logdet);
    }
}